// Round 1
// baseline (12395.975 us; speedup 1.0000x reference)
//
#include <hip/hip_runtime.h>

#define TPB 256

__device__ __forceinline__ unsigned f2ord(float f) {
    unsigned u = __float_as_uint(f);
    return (u & 0x80000000u) ? ~u : (u | 0x80000000u);
}
__device__ __forceinline__ float ord2f(unsigned u) {
    return (u & 0x80000000u) ? __uint_as_float(u & 0x7fffffffu) : __uint_as_float(~u);
}

// ---------------- node featurizer: argmax-embed + 17->24 affine ----------------
__global__ void k_node(const float* __restrict__ x, const float* __restrict__ emb,
                       const float* __restrict__ nw, const float* __restrict__ nb,
                       float* __restrict__ h, int N, int XW, int NA) {
    __shared__ float s_w[24 * 17];
    __shared__ float s_b[24];
    for (int t = threadIdx.x; t < 24 * 17; t += blockDim.x) s_w[t] = nw[t];
    for (int t = threadIdx.x; t < 24; t += blockDim.x) s_b[t] = nb[t];
    __syncthreads();
    int n = blockIdx.x * blockDim.x + threadIdx.x;
    if (n >= N) return;
    const float* row = x + (size_t)n * XW;
    float best = row[0]; int bi = 0;
    for (int i = 1; i < NA; ++i) { float v = row[i]; if (v > best) { best = v; bi = i; } }
    float f[17];
    const float* er = emb + bi * 16;
    #pragma unroll
    for (int j = 0; j < 16; ++j) f[j] = er[j];
    f[16] = row[XW - 1];
    float* hr = h + (size_t)n * 24;
    #pragma unroll
    for (int k = 0; k < 24; ++k) {
        float a = s_b[k];
        #pragma unroll
        for (int j = 0; j < 17; ++j) a = fmaf(s_w[k * 17 + j], f[j], a);
        hr[k] = a;
    }
}

// ---------------- self-loop raw-attr sums: slsum[d] += attr, slcnt[d]++ ----------------
__global__ void k_slsum(const int* __restrict__ ei, const float* __restrict__ attr,
                        float* __restrict__ slsum, int* __restrict__ slcnt,
                        int E2, int EU) {
    int e = blockIdx.x * blockDim.x + threadIdx.x;
    if (e >= E2) return;
    int d = ei[E2 + e];
    int ar = (e < EU) ? e : e - EU;
    float4 v = *(const float4*)(attr + (size_t)ar * 4);
    atomicAdd(&slsum[(size_t)d * 4 + 0], v.x);
    atomicAdd(&slsum[(size_t)d * 4 + 1], v.y);
    atomicAdd(&slsum[(size_t)d * 4 + 2], v.z);
    atomicAdd(&slsum[(size_t)d * 4 + 3], v.w);
    atomicAdd(&slcnt[d], 1);
}

// ---------------- per-node left/right transforms ----------------
template <int IN, int OUT>
__global__ void k_xform(const float* __restrict__ h,
                        const float* __restrict__ wl, const float* __restrict__ bl,
                        const float* __restrict__ wr, const float* __restrict__ br,
                        float* __restrict__ xl, float* __restrict__ xr, int N) {
    __shared__ float s_wl[OUT * IN], s_wr[OUT * IN], s_bl[OUT], s_br[OUT];
    for (int t = threadIdx.x; t < OUT * IN; t += blockDim.x) { s_wl[t] = wl[t]; s_wr[t] = wr[t]; }
    for (int t = threadIdx.x; t < OUT; t += blockDim.x) { s_bl[t] = bl[t]; s_br[t] = br[t]; }
    __syncthreads();
    int n = blockIdx.x * blockDim.x + threadIdx.x;
    if (n >= N) return;
    float f[IN];
    const float* hr = h + (size_t)n * IN;
    #pragma unroll
    for (int j = 0; j < IN; ++j) f[j] = hr[j];
    float* xlr = xl + (size_t)n * OUT;
    float* xrr = xr + (size_t)n * OUT;
    #pragma unroll
    for (int k = 0; k < OUT; ++k) {
        float al = s_bl[k], ar = s_br[k];
        #pragma unroll
        for (int j = 0; j < IN; ++j) {
            al = fmaf(s_wl[k * IN + j], f[j], al);
            ar = fmaf(s_wr[k * IN + j], f[j], ar);
        }
        xlr[k] = al; xrr[k] = ar;
    }
}

// ---------------- edge pass 1: logits + per-dst max ----------------
template <int OUT>
__global__ void k_edge1(const int* __restrict__ ei, const float* __restrict__ attr,
                        const float* __restrict__ slsum, const int* __restrict__ slcnt,
                        const float* __restrict__ xl, const float* __restrict__ xr,
                        const float* __restrict__ we, const float* __restrict__ ew,
                        const float* __restrict__ eb, const float* __restrict__ att,
                        float* __restrict__ logit, unsigned* __restrict__ maxb,
                        int E2, int EU, int N) {
    __shared__ float sC[OUT * 4];
    __shared__ float sCb[OUT];
    __shared__ float sAtt[OUT];
    // Fold edge MLP into the GAT edge projection: C = we @ edge_w (OUT x 4), cb = we @ edge_b
    for (int t = threadIdx.x; t < OUT * 5; t += blockDim.x) {
        int k = t / 5, c = t - k * 5;
        float a = 0.f;
        if (c < 4) { for (int j = 0; j < 12; ++j) a += we[k * 12 + j] * ew[j * 4 + c]; sC[k * 4 + c] = a; }
        else       { for (int j = 0; j < 12; ++j) a += we[k * 12 + j] * eb[j];          sCb[k] = a; }
    }
    for (int t = threadIdx.x; t < OUT; t += blockDim.x) sAtt[t] = att[t];
    __syncthreads();
    int e = blockIdx.x * blockDim.x + threadIdx.x;
    int ET = E2 + N;
    if (e >= ET) return;
    int s, d; float a0, a1, a2, a3, flag = 1.f;
    if (e < E2) {
        s = ei[e]; d = ei[E2 + e];
        int ar = (e < EU) ? e : e - EU;
        float4 v = *(const float4*)(attr + (size_t)ar * 4);
        a0 = v.x; a1 = v.y; a2 = v.z; a3 = v.w;
    } else {
        int n = e - E2; s = n; d = n;
        int c = slcnt[n];
        float4 v = *(const float4*)(slsum + (size_t)n * 4);
        float inv = (c > 0) ? 1.0f / (float)c : 0.f;
        flag = (c > 0) ? 1.f : 0.f;   // cnt==0 -> transformed mean attr is exactly 0 in the reference
        a0 = v.x * inv; a1 = v.y * inv; a2 = v.z * inv; a3 = v.w * inv;
    }
    const float4* xls = (const float4*)(xl + (size_t)s * OUT);
    const float4* xrd = (const float4*)(xr + (size_t)d * OUT);
    float lg = 0.f;
    #pragma unroll
    for (int q = 0; q < OUT / 4; ++q) {
        float4 vl = xls[q];
        float4 vr = xrd[q];
        float mm[4] = {vl.x + vr.x, vl.y + vr.y, vl.z + vr.z, vl.w + vr.w};
        #pragma unroll
        for (int r = 0; r < 4; ++r) {
            int k = 4 * q + r;
            float c = sCb[k];
            c = fmaf(sC[k * 4 + 0], a0, c);
            c = fmaf(sC[k * 4 + 1], a1, c);
            c = fmaf(sC[k * 4 + 2], a2, c);
            c = fmaf(sC[k * 4 + 3], a3, c);
            float m = mm[r] + flag * c;
            float lr = (m > 0.f) ? m : 0.2f * m;
            lg = fmaf(sAtt[k], lr, lg);
        }
    }
    logit[e] = lg;
    atomicMax(&maxb[d], f2ord(lg));
}

// ---------------- edge pass 2: p=exp(logit-max); den[d]+=p; acc[d]+=p*xl[s] ----------------
template <int OUT>
__global__ void k_edge2(const int* __restrict__ ei,
                        const float* __restrict__ xl,
                        const float* __restrict__ logit, const unsigned* __restrict__ maxb,
                        float* __restrict__ den, float* __restrict__ acc,
                        int E2, int N) {
    int e = blockIdx.x * blockDim.x + threadIdx.x;
    int ET = E2 + N;
    if (e >= ET) return;
    int s, d;
    if (e < E2) { s = ei[e]; d = ei[E2 + e]; } else { s = e - E2; d = s; }
    float p = __expf(logit[e] - ord2f(maxb[d]));
    atomicAdd(&den[d], p);
    const float4* xls = (const float4*)(xl + (size_t)s * OUT);
    float* ad = acc + (size_t)d * OUT;
    #pragma unroll
    for (int q = 0; q < OUT / 4; ++q) {
        float4 v = xls[q];
        atomicAdd(&ad[4 * q + 0], p * v.x);
        atomicAdd(&ad[4 * q + 1], p * v.y);
        atomicAdd(&ad[4 * q + 2], p * v.z);
        atomicAdd(&ad[4 * q + 3], p * v.w);
    }
}

// ---------------- node finish: h = relu(acc/den + bias) ----------------
template <int OUT>
__global__ void k_finish(const float* __restrict__ acc, const float* __restrict__ den,
                         const float* __restrict__ bias, float* __restrict__ h, int N) {
    __shared__ float s_b[OUT];
    for (int t = threadIdx.x; t < OUT; t += blockDim.x) s_b[t] = bias[t];
    __syncthreads();
    int n = blockIdx.x * blockDim.x + threadIdx.x;
    if (n >= N) return;
    float inv = 1.0f / den[n];
    const float* ar = acc + (size_t)n * OUT;
    float* hr = h + (size_t)n * OUT;
    #pragma unroll
    for (int k = 0; k < OUT; ++k) {
        float v = fmaf(ar[k], inv, s_b[k]);
        hr[k] = (v > 0.f) ? v : 0.f;
    }
}

// ---------------- mean pool (atomic) ----------------
__global__ void k_pool(const float* __restrict__ h, const int* __restrict__ batch,
                       float* __restrict__ psum, int* __restrict__ gcnt, int N) {
    int n = blockIdx.x * blockDim.x + threadIdx.x;
    if (n >= N) return;
    int g = batch[n];
    atomicAdd(&gcnt[g], 1);
    const float* hr = h + (size_t)n * 36;
    float* pr = psum + (size_t)g * 36;
    #pragma unroll
    for (int k = 0; k < 36; ++k) atomicAdd(&pr[k], hr[k]);
}

// ---------------- final head: out = (psum/max(cnt,1)) @ fw.T + fb ----------------
__global__ void k_final(const float* __restrict__ psum, const int* __restrict__ gcnt,
                        const float* __restrict__ fw, const float* __restrict__ fb,
                        float* __restrict__ out, int G) {
    int t = blockIdx.x * blockDim.x + threadIdx.x;
    if (t >= G * 64) return;
    int g = t / 64, o = t - g * 64;
    float c = (float)gcnt[g];
    if (c < 1.f) c = 1.f;
    float inv = 1.f / c;
    float a = fb[o];
    #pragma unroll
    for (int k = 0; k < 36; ++k) a = fmaf(psum[(size_t)g * 36 + k] * inv, fw[o * 36 + k], a);
    out[t] = a;
}

extern "C" void kernel_launch(void* const* d_in, const int* in_sizes, int n_in,
                              void* d_out, int out_size, void* d_ws, size_t ws_size,
                              hipStream_t stream) {
    const float* x      = (const float*)d_in[0];
    const int*   ei     = (const int*)d_in[1];
    const float* eattr  = (const float*)d_in[2];
    const int*   batch  = (const int*)d_in[3];
    const float* emb    = (const float*)d_in[4];
    const float* node_w = (const float*)d_in[5];
    const float* node_b = (const float*)d_in[6];
    const float* edge_w = (const float*)d_in[7];
    const float* edge_b = (const float*)d_in[8];
    const float* c1_wl  = (const float*)d_in[9];
    const float* c1_bl  = (const float*)d_in[10];
    const float* c1_wr  = (const float*)d_in[11];
    const float* c1_br  = (const float*)d_in[12];
    const float* c1_we  = (const float*)d_in[13];
    const float* c1_att = (const float*)d_in[14];
    const float* c1_bias= (const float*)d_in[15];
    const float* c2_wl  = (const float*)d_in[16];
    const float* c2_bl  = (const float*)d_in[17];
    const float* c2_wr  = (const float*)d_in[18];
    const float* c2_br  = (const float*)d_in[19];
    const float* c2_we  = (const float*)d_in[20];
    const float* c2_att = (const float*)d_in[21];
    const float* c2_bias= (const float*)d_in[22];
    const float* fin_w  = (const float*)d_in[23];
    const float* fin_b  = (const float*)d_in[24];
    float* out = (float*)d_out;

    const int N  = in_sizes[3];
    const int E2 = in_sizes[1] / 2;       // directed edges
    const int EU = in_sizes[2] / 4;       // undirected edges
    const int XW = in_sizes[0] / N;       // 119
    const int NA = in_sizes[4] / 16;      // 118
    const int G  = out_size / 64;         // 512
    const int ET = E2 + N;                // + self loops

    // workspace layout (floats), all 16B-aligned:
    float*    acc   = (float*)d_ws;                    // N*36
    float*    den   = acc + (size_t)N * 36;            // N
    unsigned* maxb  = (unsigned*)(den + N);            // N
    float*    slsum = (float*)(maxb + N);              // N*4
    int*      slcnt = (int*)(slsum + (size_t)N * 4);   // N
    float*    psum  = (float*)(slcnt + N);             // G*36
    int*      gcnt  = (int*)(psum + (size_t)G * 36);   // G
    float*    h     = (float*)(gcnt + G);              // N*36
    float*    xl    = h + (size_t)N * 36;              // N*36
    float*    xr    = xl + (size_t)N * 36;             // N*36
    float*    logit = xr + (size_t)N * 36;             // ET

    size_t need = ((size_t)N * 152 + (size_t)G * 37 + (size_t)E2) * 4;
    if (ws_size < need) return;  // loud failure: output stays poisoned

    // zero: acc,den,maxb,slsum,slcnt,psum,gcnt  (maxb=0 is the ordered-uint minimum)
    hipMemsetAsync(d_ws, 0, ((size_t)N * 43 + (size_t)G * 37) * 4, stream);

    dim3 b(TPB);
    dim3 gN((N + TPB - 1) / TPB);
    dim3 gE2((E2 + TPB - 1) / TPB);
    dim3 gET((ET + TPB - 1) / TPB);
    dim3 gG((G * 64 + TPB - 1) / TPB);

    k_node<<<gN, b, 0, stream>>>(x, emb, node_w, node_b, h, N, XW, NA);
    k_slsum<<<gE2, b, 0, stream>>>(ei, eattr, slsum, slcnt, E2, EU);

    // ---- layer 1 (24 -> 24) ----
    k_xform<24, 24><<<gN, b, 0, stream>>>(h, c1_wl, c1_bl, c1_wr, c1_br, xl, xr, N);
    k_edge1<24><<<gET, b, 0, stream>>>(ei, eattr, slsum, slcnt, xl, xr, c1_we, edge_w, edge_b,
                                       c1_att, logit, maxb, E2, EU, N);
    k_edge2<24><<<gET, b, 0, stream>>>(ei, xl, logit, maxb, den, acc, E2, N);
    k_finish<24><<<gN, b, 0, stream>>>(acc, den, c1_bias, h, N);

    // re-zero acc, den, maxb for layer 2
    hipMemsetAsync(d_ws, 0, (size_t)N * 38 * 4, stream);

    // ---- layer 2 (24 -> 36) ----
    k_xform<24, 36><<<gN, b, 0, stream>>>(h, c2_wl, c2_bl, c2_wr, c2_br, xl, xr, N);
    k_edge1<36><<<gET, b, 0, stream>>>(ei, eattr, slsum, slcnt, xl, xr, c2_we, edge_w, edge_b,
                                       c2_att, logit, maxb, E2, EU, N);
    k_edge2<36><<<gET, b, 0, stream>>>(ei, xl, logit, maxb, den, acc, E2, N);
    k_finish<36><<<gN, b, 0, stream>>>(acc, den, c2_bias, h, N);

    // ---- pool + head ----
    k_pool<<<gN, b, 0, stream>>>(h, batch, psum, gcnt, N);
    k_final<<<gG, b, 0, stream>>>(psum, gcnt, fin_w, fin_b, out, G);
}

// Round 2
// 3274.691 us; speedup vs baseline: 3.7854x; 3.7854x over previous
//
#include <hip/hip_runtime.h>

#define TPB 256
#define SCB 256
#define SCI 16   // scan items per thread -> 4096 per block

__device__ __forceinline__ float wred_max(float v) {
    #pragma unroll
    for (int o = 32; o >= 1; o >>= 1) v = fmaxf(v, __shfl_xor(v, o));
    return v;
}
__device__ __forceinline__ float wred_sum(float v) {
    #pragma unroll
    for (int o = 32; o >= 1; o >>= 1) v += __shfl_xor(v, o);
    return v;
}

// ---------------- node featurizer: argmax-embed + 17->24 affine ----------------
__global__ void k_node(const float* __restrict__ x, const float* __restrict__ emb,
                       const float* __restrict__ nw, const float* __restrict__ nb,
                       float* __restrict__ h, int N, int XW, int NA) {
    __shared__ float s_w[24 * 17];
    __shared__ float s_b[24];
    for (int t = threadIdx.x; t < 24 * 17; t += blockDim.x) s_w[t] = nw[t];
    for (int t = threadIdx.x; t < 24; t += blockDim.x) s_b[t] = nb[t];
    __syncthreads();
    int n = blockIdx.x * blockDim.x + threadIdx.x;
    if (n >= N) return;
    const float* row = x + (size_t)n * XW;
    float best = row[0]; int bi = 0;
    for (int i = 1; i < NA; ++i) { float v = row[i]; if (v > best) { best = v; bi = i; } }
    float f[17];
    const float* er = emb + bi * 16;
    #pragma unroll
    for (int j = 0; j < 16; ++j) f[j] = er[j];
    f[16] = row[XW - 1];
    float* hr = h + (size_t)n * 24;
    #pragma unroll
    for (int k = 0; k < 24; ++k) {
        float a = s_b[k];
        #pragma unroll
        for (int j = 0; j < 17; ++j) a = fmaf(s_w[k * 17 + j], f[j], a);
        hr[k] = a;
    }
}

// ---------------- CSR build ----------------
__global__ void k_count(const int* __restrict__ ei, int* __restrict__ indeg, int E2) {
    int e = blockIdx.x * blockDim.x + threadIdx.x;
    if (e >= E2) return;
    atomicAdd(&indeg[ei[E2 + e]], 1);
}

__global__ void k_scan_bsum(const int* __restrict__ indeg, int* __restrict__ bsum, int N) {
    int base = blockIdx.x * SCB * SCI;
    int t = threadIdx.x;
    int s = 0;
    #pragma unroll
    for (int i = 0; i < SCI; ++i) {
        int idx = base + t * SCI + i;
        if (idx < N) s += indeg[idx];
    }
    #pragma unroll
    for (int o = 32; o >= 1; o >>= 1) s += __shfl_xor(s, o);
    __shared__ int red[SCB / 64];
    if ((t & 63) == 0) red[t >> 6] = s;
    __syncthreads();
    if (t == 0) {
        int tot = 0;
        for (int w = 0; w < SCB / 64; ++w) tot += red[w];
        bsum[blockIdx.x] = tot;
    }
}

__global__ void k_scan_final(const int* __restrict__ indeg, const int* __restrict__ bsum,
                             int* __restrict__ rowptr, int N, int nb) {
    __shared__ int s_t[SCB];
    __shared__ int s_boff;
    int base = blockIdx.x * SCB * SCI;
    int t = threadIdx.x;
    if (t == 0) {
        int off = 0;
        for (int i = 0; i < (int)blockIdx.x; ++i) off += bsum[i];
        s_boff = off;
        if (blockIdx.x == 0) {
            int tot = 0;
            for (int i = 0; i < nb; ++i) tot += bsum[i];
            rowptr[N] = tot;
        }
    }
    int loc[SCI]; int s = 0;
    #pragma unroll
    for (int i = 0; i < SCI; ++i) {
        int idx = base + t * SCI + i;
        int v = (idx < N) ? indeg[idx] : 0;
        loc[i] = s; s += v;
    }
    s_t[t] = s;
    __syncthreads();
    for (int o = 1; o < SCB; o <<= 1) {
        int v = (t >= o) ? s_t[t - o] : 0;
        __syncthreads();
        s_t[t] += v;
        __syncthreads();
    }
    int toff = ((t > 0) ? s_t[t - 1] : 0) + s_boff;
    #pragma unroll
    for (int i = 0; i < SCI; ++i) {
        int idx = base + t * SCI + i;
        if (idx < N) rowptr[idx] = toff + loc[i];
    }
}

__global__ void k_cursor(const int* __restrict__ rowptr, int* __restrict__ cursor, int N) {
    int n = blockIdx.x * blockDim.x + threadIdx.x;
    if (n < N) cursor[n] = rowptr[n];
}

__global__ void k_scatter(const int* __restrict__ ei, int* __restrict__ cursor,
                          int* __restrict__ csr_src, int* __restrict__ csr_aid,
                          int E2, int EU) {
    int e = blockIdx.x * blockDim.x + threadIdx.x;
    if (e >= E2) return;
    int s = ei[e];
    int d = ei[E2 + e];
    int pos = atomicAdd(&cursor[d], 1);
    csr_src[pos] = s;
    csr_aid[pos] = (e < EU) ? e : e - EU;
}

// ---------------- per-node left/right transforms ----------------
template <int IN, int OUT>
__global__ void k_xform(const float* __restrict__ h,
                        const float* __restrict__ wl, const float* __restrict__ bl,
                        const float* __restrict__ wr, const float* __restrict__ br,
                        float* __restrict__ xl, float* __restrict__ xr, int N) {
    __shared__ float s_wl[OUT * IN], s_wr[OUT * IN], s_bl[OUT], s_br[OUT];
    for (int t = threadIdx.x; t < OUT * IN; t += blockDim.x) { s_wl[t] = wl[t]; s_wr[t] = wr[t]; }
    for (int t = threadIdx.x; t < OUT; t += blockDim.x) { s_bl[t] = bl[t]; s_br[t] = br[t]; }
    __syncthreads();
    int n = blockIdx.x * blockDim.x + threadIdx.x;
    if (n >= N) return;
    float f[IN];
    const float* hr = h + (size_t)n * IN;
    #pragma unroll
    for (int j = 0; j < IN; ++j) f[j] = hr[j];
    float* xlr = xl + (size_t)n * OUT;
    float* xrr = xr + (size_t)n * OUT;
    #pragma unroll
    for (int k = 0; k < OUT; ++k) {
        float al = s_bl[k], ar = s_br[k];
        #pragma unroll
        for (int j = 0; j < IN; ++j) {
            al = fmaf(s_wl[k * IN + j], f[j], al);
            ar = fmaf(s_wr[k * IN + j], f[j], ar);
        }
        xlr[k] = al; xrr[k] = ar;
    }
}

// ---------------- fused GATv2 edge+softmax+aggregate: one wave per node ----------------
// Phase A (lanes = edges): gather xl[src] row, compute logit inline, stage row+p in LDS.
// Online softmax across 64-edge chunks. Phase B (lanes = channels): acc += p_t * xl_t[k].
// Self-loop folded in at the end (attr mean accumulated during Phase A).
template <int OUT>
__global__ void k_gat(const int* __restrict__ rowptr, const int* __restrict__ csr_src,
                      const int* __restrict__ csr_aid, const float* __restrict__ attr,
                      const float* __restrict__ xl, const float* __restrict__ xr,
                      const float* __restrict__ we, const float* __restrict__ ew,
                      const float* __restrict__ eb, const float* __restrict__ att,
                      const float* __restrict__ bias, float* __restrict__ h, int N) {
    __shared__ float sC[OUT * 4], sCb[OUT], sAtt[OUT], sB[OUT];
    __shared__ float sXL[4][OUT * 65];   // [wave][channel*65 + edge_lane], 65-stride = conflict-free both phases
    __shared__ float sP[4][64];
    // fold edge MLP into GAT edge projection: C = we @ edge_w (OUT x 4), cb = we @ edge_b
    for (int t = threadIdx.x; t < OUT * 5; t += blockDim.x) {
        int k = t / 5, c = t - k * 5;
        float a = 0.f;
        if (c < 4) { for (int j = 0; j < 12; ++j) a += we[k * 12 + j] * ew[j * 4 + c]; sC[k * 4 + c] = a; }
        else       { for (int j = 0; j < 12; ++j) a += we[k * 12 + j] * eb[j];          sCb[k] = a; }
    }
    for (int t = threadIdx.x; t < OUT; t += blockDim.x) { sAtt[t] = att[t]; sB[t] = bias[t]; }
    __syncthreads();

    int wid = threadIdx.x >> 6, lane = threadIdx.x & 63;
    int n = blockIdx.x * 4 + wid;
    if (n >= N) return;   // wave-uniform; no syncthreads after this point

    float* myXL = &sXL[wid][0];
    float* myP  = &sP[wid][0];

    int rb = rowptr[n], re = rowptr[n + 1];

    // xr row of this node: broadcast load into registers (shared by all edges)
    float xrr[OUT];
    const float4* xr4 = (const float4*)(xr + (size_t)n * OUT);
    #pragma unroll
    for (int q = 0; q < OUT / 4; ++q) {
        float4 v = xr4[q];
        xrr[4 * q + 0] = v.x; xrr[4 * q + 1] = v.y; xrr[4 * q + 2] = v.z; xrr[4 * q + 3] = v.w;
    }

    float m = -INFINITY, den = 0.f, acc = 0.f;
    float as0 = 0.f, as1 = 0.f, as2 = 0.f, as3 = 0.f;   // raw-attr sums for self-loop mean

    for (int c0 = rb; c0 < re; c0 += 64) {
        int j = c0 + lane;
        float lg = -INFINITY;
        if (j < re) {
            int s = csr_src[j], aid = csr_aid[j];
            float4 av = *(const float4*)(attr + (size_t)aid * 4);
            as0 += av.x; as1 += av.y; as2 += av.z; as3 += av.w;
            const float4* xs4 = (const float4*)(xl + (size_t)s * OUT);
            lg = 0.f;
            #pragma unroll
            for (int q = 0; q < OUT / 4; ++q) {
                float4 v = xs4[q];
                float e0 = v.x, e1 = v.y, e2 = v.z, e3 = v.w;
                myXL[(4 * q + 0) * 65 + lane] = e0;
                myXL[(4 * q + 1) * 65 + lane] = e1;
                myXL[(4 * q + 2) * 65 + lane] = e2;
                myXL[(4 * q + 3) * 65 + lane] = e3;
                #pragma unroll
                for (int r = 0; r < 4; ++r) {
                    int k = 4 * q + r;
                    float xlv = (r == 0) ? e0 : (r == 1) ? e1 : (r == 2) ? e2 : e3;
                    float c = sCb[k];
                    c = fmaf(sC[k * 4 + 0], av.x, c);
                    c = fmaf(sC[k * 4 + 1], av.y, c);
                    c = fmaf(sC[k * 4 + 2], av.z, c);
                    c = fmaf(sC[k * 4 + 3], av.w, c);
                    float mm = xlv + xrr[k] + c;
                    float lr = (mm > 0.f) ? mm : 0.2f * mm;
                    lg = fmaf(sAtt[k], lr, lg);
                }
            }
        }
        float cm = wred_max(lg);
        float nm = fmaxf(m, cm);
        float sc = __expf(m - nm);          // m=-inf on first chunk -> 0
        float p = (j < re) ? __expf(lg - nm) : 0.f;
        myP[lane] = p;
        float ps = wred_sum(p);
        den = den * sc + ps;
        acc *= sc;
        m = nm;
        int cnt = min(64, re - c0);
        if (lane < OUT) {
            for (int t = 0; t < cnt; ++t)
                acc = fmaf(myP[t], myXL[lane * 65 + t], acc);
        }
    }

    // self-loop: attr = mean of incoming transformed attrs (0-vector if indeg==0)
    as0 = wred_sum(as0); as1 = wred_sum(as1); as2 = wred_sum(as2); as3 = wred_sum(as3);
    int cnt = re - rb;
    float inv  = (cnt > 0) ? 1.f / (float)cnt : 0.f;
    float flag = (cnt > 0) ? 1.f : 0.f;
    float a0 = as0 * inv, a1 = as1 * inv, a2 = as2 * inv, a3 = as3 * inv;

    float xln = 0.f, contrib = 0.f, xrv = 0.f;
    if (lane < OUT) {
        xln = xl[(size_t)n * OUT + lane];
        xrv = xr[(size_t)n * OUT + lane];   // coalesced re-read (avoids dynamic reg-index of xrr)
        float c = sCb[lane];
        c = fmaf(sC[lane * 4 + 0], a0, c);
        c = fmaf(sC[lane * 4 + 1], a1, c);
        c = fmaf(sC[lane * 4 + 2], a2, c);
        c = fmaf(sC[lane * 4 + 3], a3, c);
        float mm = xln + xrv + flag * c;
        float lr = (mm > 0.f) ? mm : 0.2f * mm;
        contrib = sAtt[lane] * lr;
    }
    float lgs = wred_sum(contrib);
    float nm = fmaxf(m, lgs);
    float sc = __expf(m - nm);
    float p  = __expf(lgs - nm);
    den = den * sc + p;                      // den >= p > 0: no div-by-zero
    if (lane < OUT) {
        acc = acc * sc + p * xln;
        float v = acc / den + sB[lane];
        h[(size_t)n * OUT + lane] = (v > 0.f) ? v : 0.f;
    }
}

// ---------------- mean pool: one block per graph, batch is sorted ----------------
__global__ void k_pool(const float* __restrict__ h, const int* __restrict__ batch,
                       float* __restrict__ pmean, int N) {
    int g = blockIdx.x;
    int a = 0, b = N;
    while (a < b) { int mid = (a + b) >> 1; if (batch[mid] < g) a = mid + 1; else b = mid; }
    int lo = a;
    a = lo; b = N;
    while (a < b) { int mid = (a + b) >> 1; if (batch[mid] < g + 1) a = mid + 1; else b = mid; }
    int hi = a;
    int cnt = hi - lo;
    int wid = threadIdx.x >> 6, lane = threadIdx.x & 63;
    float acc = 0.f;
    if (lane < 36) {
        for (int n = lo + wid; n < hi; n += 4) acc += h[(size_t)n * 36 + lane];
    }
    __shared__ float s_acc[4][36];
    if (lane < 36) s_acc[wid][lane] = acc;
    __syncthreads();
    if (threadIdx.x < 36) {
        float v = s_acc[0][threadIdx.x] + s_acc[1][threadIdx.x] +
                  s_acc[2][threadIdx.x] + s_acc[3][threadIdx.x];
        float iv = (cnt > 0) ? 1.f / (float)cnt : 0.f;
        pmean[(size_t)g * 36 + threadIdx.x] = v * iv;
    }
}

// ---------------- final head ----------------
__global__ void k_final(const float* __restrict__ pmean,
                        const float* __restrict__ fw, const float* __restrict__ fb,
                        float* __restrict__ out, int G) {
    int t = blockIdx.x * blockDim.x + threadIdx.x;
    if (t >= G * 64) return;
    int g = t / 64, o = t - g * 64;
    float a = fb[o];
    #pragma unroll
    for (int k = 0; k < 36; ++k) a = fmaf(pmean[(size_t)g * 36 + k], fw[o * 36 + k], a);
    out[t] = a;
}

extern "C" void kernel_launch(void* const* d_in, const int* in_sizes, int n_in,
                              void* d_out, int out_size, void* d_ws, size_t ws_size,
                              hipStream_t stream) {
    const float* x      = (const float*)d_in[0];
    const int*   ei     = (const int*)d_in[1];
    const float* eattr  = (const float*)d_in[2];
    const int*   batch  = (const int*)d_in[3];
    const float* emb    = (const float*)d_in[4];
    const float* node_w = (const float*)d_in[5];
    const float* node_b = (const float*)d_in[6];
    const float* edge_w = (const float*)d_in[7];
    const float* edge_b = (const float*)d_in[8];
    const float* c1_wl  = (const float*)d_in[9];
    const float* c1_bl  = (const float*)d_in[10];
    const float* c1_wr  = (const float*)d_in[11];
    const float* c1_br  = (const float*)d_in[12];
    const float* c1_we  = (const float*)d_in[13];
    const float* c1_att = (const float*)d_in[14];
    const float* c1_bias= (const float*)d_in[15];
    const float* c2_wl  = (const float*)d_in[16];
    const float* c2_bl  = (const float*)d_in[17];
    const float* c2_wr  = (const float*)d_in[18];
    const float* c2_br  = (const float*)d_in[19];
    const float* c2_we  = (const float*)d_in[20];
    const float* c2_att = (const float*)d_in[21];
    const float* c2_bias= (const float*)d_in[22];
    const float* fin_w  = (const float*)d_in[23];
    const float* fin_b  = (const float*)d_in[24];
    float* out = (float*)d_out;

    const int N  = in_sizes[3];
    const int E2 = in_sizes[1] / 2;
    const int EU = in_sizes[2] / 4;
    const int XW = in_sizes[0] / N;
    const int NA = in_sizes[4] / 16;
    const int G  = out_size / 64;

    // workspace layout (4B elements)
    float* h      = (float*)d_ws;                        // N*36
    float* xl     = h + (size_t)N * 36;                  // N*36
    float* xr     = xl + (size_t)N * 36;                 // N*36
    float* pmean  = xr + (size_t)N * 36;                 // G*36
    int*   rowptr = (int*)(pmean + (size_t)G * 36);      // N+1
    int*   cursor = rowptr + (N + 1);                    // N (also indeg)
    int*   csr_src= cursor + N;                          // E2
    int*   csr_aid= csr_src + (size_t)E2;                // E2
    int*   bsum   = csr_aid + (size_t)E2;                // 64

    size_t need = ((size_t)N * 110 + (size_t)G * 36 + 2 * (size_t)E2 + N + 65) * 4;
    if (ws_size < need) return;  // loud failure: output stays poisoned

    hipMemsetAsync(cursor, 0, (size_t)N * 4, stream);

    dim3 b(TPB);
    dim3 gN((N + TPB - 1) / TPB);
    dim3 gE((E2 + TPB - 1) / TPB);
    int nb = (N + SCB * SCI - 1) / (SCB * SCI);

    k_node<<<gN, b, 0, stream>>>(x, emb, node_w, node_b, h, N, XW, NA);
    k_count<<<gE, b, 0, stream>>>(ei, cursor, E2);
    k_scan_bsum<<<nb, SCB, 0, stream>>>(cursor, bsum, N);
    k_scan_final<<<nb, SCB, 0, stream>>>(cursor, bsum, rowptr, N, nb);
    k_cursor<<<gN, b, 0, stream>>>(rowptr, cursor, N);
    k_scatter<<<gE, b, 0, stream>>>(ei, cursor, csr_src, csr_aid, E2, EU);

    dim3 gW((N + 3) / 4);   // 4 waves per block, 1 wave per node

    // ---- layer 1 (24 -> 24) ----
    k_xform<24, 24><<<gN, b, 0, stream>>>(h, c1_wl, c1_bl, c1_wr, c1_br, xl, xr, N);
    k_gat<24><<<gW, b, 0, stream>>>(rowptr, csr_src, csr_aid, eattr, xl, xr,
                                    c1_we, edge_w, edge_b, c1_att, c1_bias, h, N);

    // ---- layer 2 (24 -> 36) ----
    k_xform<24, 36><<<gN, b, 0, stream>>>(h, c2_wl, c2_bl, c2_wr, c2_br, xl, xr, N);
    k_gat<36><<<gW, b, 0, stream>>>(rowptr, csr_src, csr_aid, eattr, xl, xr,
                                    c2_we, edge_w, edge_b, c2_att, c2_bias, h, N);

    // ---- pool + head ----
    k_pool<<<G, b, 0, stream>>>(h, batch, pmean, N);
    k_final<<<(G * 64 + TPB - 1) / TPB, b, 0, stream>>>(pmean, fin_w, fin_b, out, G);
}

// Round 5
// 2817.029 us; speedup vs baseline: 4.4004x; 1.1625x over previous
//
#include <hip/hip_runtime.h>

#define TPB 256
#define SCB 256
#define SCI 16   // scan items per thread -> 4096 per block

__device__ __forceinline__ float wred_max(float v) {
    #pragma unroll
    for (int o = 32; o >= 1; o >>= 1) v = fmaxf(v, __shfl_xor(v, o));
    return v;
}
__device__ __forceinline__ float wred_sum(float v) {
    #pragma unroll
    for (int o = 32; o >= 1; o >>= 1) v += __shfl_xor(v, o);
    return v;
}

// ---------------- node featurizer: argmax-embed + 17->24 affine ----------------
__global__ void k_node(const float* __restrict__ x, const float* __restrict__ emb,
                       const float* __restrict__ nw, const float* __restrict__ nb,
                       float* __restrict__ h, int N, int XW, int NA) {
    __shared__ float s_w[24 * 17];
    __shared__ float s_b[24];
    for (int t = threadIdx.x; t < 24 * 17; t += blockDim.x) s_w[t] = nw[t];
    for (int t = threadIdx.x; t < 24; t += blockDim.x) s_b[t] = nb[t];
    __syncthreads();
    int n = blockIdx.x * blockDim.x + threadIdx.x;
    if (n >= N) return;
    const float* row = x + (size_t)n * XW;
    float best = row[0]; int bi = 0;
    for (int i = 1; i < NA; ++i) { float v = row[i]; if (v > best) { best = v; bi = i; } }
    float f[17];
    const float* er = emb + bi * 16;
    #pragma unroll
    for (int j = 0; j < 16; ++j) f[j] = er[j];
    f[16] = row[XW - 1];
    float* hr = h + (size_t)n * 24;
    #pragma unroll
    for (int k = 0; k < 24; ++k) {
        float a = s_b[k];
        #pragma unroll
        for (int j = 0; j < 17; ++j) a = fmaf(s_w[k * 17 + j], f[j], a);
        hr[k] = a;
    }
}

// ---------------- CSR build ----------------
__global__ void k_count(const int* __restrict__ ei, int* __restrict__ indeg, int E2) {
    int e = blockIdx.x * blockDim.x + threadIdx.x;
    if (e >= E2) return;
    atomicAdd(&indeg[ei[E2 + e]], 1);
}

__global__ void k_scan_bsum(const int* __restrict__ indeg, int* __restrict__ bsum, int N) {
    int base = blockIdx.x * SCB * SCI;
    int t = threadIdx.x;
    int s = 0;
    #pragma unroll
    for (int i = 0; i < SCI; ++i) {
        int idx = base + t * SCI + i;
        if (idx < N) s += indeg[idx];
    }
    #pragma unroll
    for (int o = 32; o >= 1; o >>= 1) s += __shfl_xor(s, o);
    __shared__ int red[SCB / 64];
    if ((t & 63) == 0) red[t >> 6] = s;
    __syncthreads();
    if (t == 0) {
        int tot = 0;
        for (int w = 0; w < SCB / 64; ++w) tot += red[w];
        bsum[blockIdx.x] = tot;
    }
}

__global__ void k_scan_final(const int* __restrict__ indeg, const int* __restrict__ bsum,
                             int* __restrict__ rowptr, int N, int nb) {
    __shared__ int s_t[SCB];
    __shared__ int s_boff;
    int base = blockIdx.x * SCB * SCI;
    int t = threadIdx.x;
    if (t == 0) {
        int off = 0;
        for (int i = 0; i < (int)blockIdx.x; ++i) off += bsum[i];
        s_boff = off;
        if (blockIdx.x == 0) {
            int tot = 0;
            for (int i = 0; i < nb; ++i) tot += bsum[i];
            rowptr[N] = tot;
        }
    }
    int loc[SCI]; int s = 0;
    #pragma unroll
    for (int i = 0; i < SCI; ++i) {
        int idx = base + t * SCI + i;
        int v = (idx < N) ? indeg[idx] : 0;
        loc[i] = s; s += v;
    }
    s_t[t] = s;
    __syncthreads();
    for (int o = 1; o < SCB; o <<= 1) {
        int v = (t >= o) ? s_t[t - o] : 0;
        __syncthreads();
        s_t[t] += v;
        __syncthreads();
    }
    int toff = ((t > 0) ? s_t[t - 1] : 0) + s_boff;
    #pragma unroll
    for (int i = 0; i < SCI; ++i) {
        int idx = base + t * SCI + i;
        if (idx < N) rowptr[idx] = toff + loc[i];
    }
}

__global__ void k_cursor(const int* __restrict__ rowptr, int* __restrict__ cursor, int N) {
    int n = blockIdx.x * blockDim.x + threadIdx.x;
    if (n < N) cursor[n] = rowptr[n];
}

__global__ void k_scatter(const int* __restrict__ ei, int* __restrict__ cursor,
                          int* __restrict__ csr_src, int* __restrict__ csr_aid,
                          int E2, int EU) {
    int e = blockIdx.x * blockDim.x + threadIdx.x;
    if (e >= E2) return;
    int s = ei[e];
    int d = ei[E2 + e];
    int pos = atomicAdd(&cursor[d], 1);
    csr_src[pos] = s;
    csr_aid[pos] = (e < EU) ? e : e - EU;
}

// ---------------- per-node left/right transforms (both fp32) ----------------
template <int IN, int OUT>
__global__ void k_xform(const float* __restrict__ h,
                        const float* __restrict__ wl, const float* __restrict__ bl,
                        const float* __restrict__ wr, const float* __restrict__ br,
                        float* __restrict__ xl, float* __restrict__ xr, int N) {
    __shared__ float s_wl[OUT * IN], s_wr[OUT * IN], s_bl[OUT], s_br[OUT];
    for (int t = threadIdx.x; t < OUT * IN; t += blockDim.x) { s_wl[t] = wl[t]; s_wr[t] = wr[t]; }
    for (int t = threadIdx.x; t < OUT; t += blockDim.x) { s_bl[t] = bl[t]; s_br[t] = br[t]; }
    __syncthreads();
    int n = blockIdx.x * blockDim.x + threadIdx.x;
    if (n >= N) return;
    float f[IN];
    const float* hr = h + (size_t)n * IN;
    #pragma unroll
    for (int j = 0; j < IN; ++j) f[j] = hr[j];
    float* xlr = xl + (size_t)n * OUT;
    float* xrr = xr + (size_t)n * OUT;
    #pragma unroll
    for (int k = 0; k < OUT; ++k) {
        float al = s_bl[k], ar = s_br[k];
        #pragma unroll
        for (int j = 0; j < IN; ++j) {
            al = fmaf(s_wl[k * IN + j], f[j], al);
            ar = fmaf(s_wr[k * IN + j], f[j], ar);
        }
        xlr[k] = al; xrr[k] = ar;
    }
}

// ---------------- fused GATv2: one wave per node, fp32 ----------------
// Phase A (lanes = edges): gather xl[src] row float4-wise -> LDS (channel-major,
// 65-dword stride, conflict-free) + logit inline (xr+cb row staged in per-wave LDS,
// no big register arrays -> no spills). Online softmax via wave reductions; p is
// broadcast through per-wave LDS sP (written by ALL 64 lanes while convergent --
// NOT __shfl, whose ds_bpermute reads from inactive lanes are undefined under the
// lane<OUT divergence; that was rounds 3/4's bug). Phase B (lanes = channels):
// dual-accumulator FMA over staged rows. Self-loop folded at the end.
template <int OUT, int MINW>
__launch_bounds__(256, MINW)
__global__ void k_gat(const int* __restrict__ rowptr, const int* __restrict__ csr_src,
                      const int* __restrict__ csr_aid, const float* __restrict__ attr,
                      const float* __restrict__ xl, const float* __restrict__ xr,
                      const float* __restrict__ we, const float* __restrict__ ew,
                      const float* __restrict__ eb, const float* __restrict__ att,
                      const float* __restrict__ bias, float* __restrict__ h, int N) {
    __shared__ float sC[OUT * 4], sCb[OUT], sAtt[OUT], sB[OUT];
    __shared__ float sXB[4][OUT];        // xr row + sCb, per wave
    __shared__ float sXL[4][OUT * 65];   // staged rows, channel-major, stride 65 = conflict-free
    __shared__ float sP[4][64];          // per-wave p broadcast (all-lane write)
    // fold edge MLP into GAT edge projection: C = we @ edge_w (OUT x 4), cb = we @ edge_b
    for (int t = threadIdx.x; t < OUT * 5; t += blockDim.x) {
        int k = t / 5, c = t - k * 5;
        float a = 0.f;
        if (c < 4) { for (int j = 0; j < 12; ++j) a += we[k * 12 + j] * ew[j * 4 + c]; sC[k * 4 + c] = a; }
        else       { for (int j = 0; j < 12; ++j) a += we[k * 12 + j] * eb[j];          sCb[k] = a; }
    }
    for (int t = threadIdx.x; t < OUT; t += blockDim.x) { sAtt[t] = att[t]; sB[t] = bias[t]; }
    __syncthreads();

    int wid = threadIdx.x >> 6, lane = threadIdx.x & 63;
    int n = blockIdx.x * 4 + wid;
    if (n >= N) return;   // wave-uniform; no syncthreads after this point

    if (lane < OUT) sXB[wid][lane] = xr[(size_t)n * OUT + lane] + sCb[lane];

    float* myXL = &sXL[wid][0];
    float* myP  = &sP[wid][0];
    int rb = rowptr[n], re = rowptr[n + 1];

    float m = -INFINITY, den = 0.f, acc = 0.f;
    float as0 = 0.f, as1 = 0.f, as2 = 0.f, as3 = 0.f;   // raw-attr sums for self-loop mean

    for (int c0 = rb; c0 < re; c0 += 64) {
        int j = c0 + lane;
        float lg = -INFINITY;
        if (j < re) {
            int s = csr_src[j], aid = csr_aid[j];
            float4 av = *(const float4*)(attr + (size_t)aid * 4);
            as0 += av.x; as1 += av.y; as2 += av.z; as3 += av.w;
            const float4* xs4 = (const float4*)(xl + (size_t)s * OUT);
            lg = 0.f;
            #pragma unroll
            for (int q4 = 0; q4 < OUT / 4; ++q4) {
                float4 v = xs4[q4];
                myXL[(4 * q4 + 0) * 65 + lane] = v.x;
                myXL[(4 * q4 + 1) * 65 + lane] = v.y;
                myXL[(4 * q4 + 2) * 65 + lane] = v.z;
                myXL[(4 * q4 + 3) * 65 + lane] = v.w;
                #pragma unroll
                for (int r = 0; r < 4; ++r) {
                    int k = 4 * q4 + r;
                    float xlv = (r == 0) ? v.x : (r == 1) ? v.y : (r == 2) ? v.z : v.w;
                    float c = sXB[wid][k];
                    c = fmaf(sC[k * 4 + 0], av.x, c);
                    c = fmaf(sC[k * 4 + 1], av.y, c);
                    c = fmaf(sC[k * 4 + 2], av.z, c);
                    c = fmaf(sC[k * 4 + 3], av.w, c);
                    float mm = xlv + c;
                    float lr = (mm > 0.f) ? mm : 0.2f * mm;
                    lg = fmaf(sAtt[k], lr, lg);
                }
            }
        }
        float cm = wred_max(lg);
        float nm = fmaxf(m, cm);
        float sc = __expf(m - nm);          // m=-inf on first chunk -> 0
        float p = (j < re) ? __expf(lg - nm) : 0.f;
        myP[lane] = p;                      // ALL 64 lanes write (convergent)
        float ps = wred_sum(p);
        den = den * sc + ps;
        m = nm;
        int cnt = min(64, re - c0);
        if (lane < OUT) {
            float a0 = 0.f, a1 = 0.f;
            int t = 0;
            for (; t + 1 < cnt; t += 2) {
                a0 = fmaf(myP[t],     myXL[lane * 65 + t],     a0);
                a1 = fmaf(myP[t + 1], myXL[lane * 65 + t + 1], a1);
            }
            if (t < cnt) a0 = fmaf(myP[t], myXL[lane * 65 + t], a0);
            acc = fmaf(acc, sc, a0 + a1);
        }
    }

    // self-loop: attr = mean of incoming TRANSFORMED attrs (exact-0 if indeg==0)
    as0 = wred_sum(as0); as1 = wred_sum(as1); as2 = wred_sum(as2); as3 = wred_sum(as3);
    int cnt = re - rb;
    float inv = (cnt > 0) ? 1.f / (float)cnt : 0.f;
    float a0 = as0 * inv, a1 = as1 * inv, a2 = as2 * inv, a3 = as3 * inv;

    float xln = 0.f, contrib = 0.f;
    if (lane < OUT) {
        xln = xl[(size_t)n * OUT + lane];
        float dot = 0.f;
        dot = fmaf(sC[lane * 4 + 0], a0, dot);
        dot = fmaf(sC[lane * 4 + 1], a1, dot);
        dot = fmaf(sC[lane * 4 + 2], a2, dot);
        dot = fmaf(sC[lane * 4 + 3], a3, dot);
        // sXB = xr + sCb; when indeg==0 the transformed self attr is 0 -> remove sCb
        float mm = xln + sXB[wid][lane] + ((cnt > 0) ? dot : -sCb[lane]);
        float lr = (mm > 0.f) ? mm : 0.2f * mm;
        contrib = sAtt[lane] * lr;
    }
    float lgs = wred_sum(contrib);
    float nm = fmaxf(m, lgs);
    float sc = __expf(m - nm);
    float p = __expf(lgs - nm);
    den = den * sc + p;                      // den >= p > 0: no div-by-zero
    if (lane < OUT) {
        acc = acc * sc + p * xln;
        float v = acc / den + sB[lane];
        h[(size_t)n * OUT + lane] = (v > 0.f) ? v : 0.f;
    }
}

// ---------------- mean pool: one block per graph, batch is sorted ----------------
__global__ void k_pool(const float* __restrict__ h, const int* __restrict__ batch,
                       float* __restrict__ pmean, int N) {
    int g = blockIdx.x;
    int a = 0, b = N;
    while (a < b) { int mid = (a + b) >> 1; if (batch[mid] < g) a = mid + 1; else b = mid; }
    int lo = a;
    a = lo; b = N;
    while (a < b) { int mid = (a + b) >> 1; if (batch[mid] < g + 1) a = mid + 1; else b = mid; }
    int hi = a;
    int cnt = hi - lo;
    int wid = threadIdx.x >> 6, lane = threadIdx.x & 63;
    float acc = 0.f;
    if (lane < 36) {
        for (int n = lo + wid; n < hi; n += 4) acc += h[(size_t)n * 36 + lane];
    }
    __shared__ float s_acc[4][36];
    if (lane < 36) s_acc[wid][lane] = acc;
    __syncthreads();
    if (threadIdx.x < 36) {
        float v = s_acc[0][threadIdx.x] + s_acc[1][threadIdx.x] +
                  s_acc[2][threadIdx.x] + s_acc[3][threadIdx.x];
        float iv = (cnt > 0) ? 1.f / (float)cnt : 0.f;
        pmean[(size_t)g * 36 + threadIdx.x] = v * iv;
    }
}

// ---------------- final head ----------------
__global__ void k_final(const float* __restrict__ pmean,
                        const float* __restrict__ fw, const float* __restrict__ fb,
                        float* __restrict__ out, int G) {
    int t = blockIdx.x * blockDim.x + threadIdx.x;
    if (t >= G * 64) return;
    int g = t / 64, o = t - g * 64;
    float a = fb[o];
    #pragma unroll
    for (int k = 0; k < 36; ++k) a = fmaf(pmean[(size_t)g * 36 + k], fw[o * 36 + k], a);
    out[t] = a;
}

extern "C" void kernel_launch(void* const* d_in, const int* in_sizes, int n_in,
                              void* d_out, int out_size, void* d_ws, size_t ws_size,
                              hipStream_t stream) {
    const float* x      = (const float*)d_in[0];
    const int*   ei     = (const int*)d_in[1];
    const float* eattr  = (const float*)d_in[2];
    const int*   batch  = (const int*)d_in[3];
    const float* emb    = (const float*)d_in[4];
    const float* node_w = (const float*)d_in[5];
    const float* node_b = (const float*)d_in[6];
    const float* edge_w = (const float*)d_in[7];
    const float* edge_b = (const float*)d_in[8];
    const float* c1_wl  = (const float*)d_in[9];
    const float* c1_bl  = (const float*)d_in[10];
    const float* c1_wr  = (const float*)d_in[11];
    const float* c1_br  = (const float*)d_in[12];
    const float* c1_we  = (const float*)d_in[13];
    const float* c1_att = (const float*)d_in[14];
    const float* c1_bias= (const float*)d_in[15];
    const float* c2_wl  = (const float*)d_in[16];
    const float* c2_bl  = (const float*)d_in[17];
    const float* c2_wr  = (const float*)d_in[18];
    const float* c2_br  = (const float*)d_in[19];
    const float* c2_we  = (const float*)d_in[20];
    const float* c2_att = (const float*)d_in[21];
    const float* c2_bias= (const float*)d_in[22];
    const float* fin_w  = (const float*)d_in[23];
    const float* fin_b  = (const float*)d_in[24];
    float* out = (float*)d_out;

    const int N  = in_sizes[3];
    const int E2 = in_sizes[1] / 2;
    const int EU = in_sizes[2] / 4;
    const int XW = in_sizes[0] / N;
    const int NA = in_sizes[4] / 16;
    const int G  = out_size / 64;

    // workspace layout (4B units); all segments 16B-aligned
    float*  h      = (float*)d_ws;                       // N*36
    float*  xl     = h + (size_t)N * 36;                 // N*36
    float*  xr     = xl + (size_t)N * 36;                // N*36
    float*  pmean  = xr + (size_t)N * 36;                // G*36
    int*    rowptr = (int*)(pmean + (size_t)G * 36);     // N+1
    int*    cursor = rowptr + (N + 1);                   // N (also indeg)
    int*    csr_src= cursor + N;                         // E2
    int*    csr_aid= csr_src + (size_t)E2;               // E2
    int*    bsum   = csr_aid + (size_t)E2;               // 64

    size_t need = ((size_t)N * 109 + (size_t)G * 36 + 2 * (size_t)E2 + 65 + 64) * 4;
    if (ws_size < need) return;  // loud failure: output stays poisoned

    hipMemsetAsync(cursor, 0, (size_t)N * 4, stream);

    dim3 b(TPB);
    dim3 gN((N + TPB - 1) / TPB);
    dim3 gE((E2 + TPB - 1) / TPB);
    int nb = (N + SCB * SCI - 1) / (SCB * SCI);

    k_node<<<gN, b, 0, stream>>>(x, emb, node_w, node_b, h, N, XW, NA);
    k_count<<<gE, b, 0, stream>>>(ei, cursor, E2);
    k_scan_bsum<<<nb, SCB, 0, stream>>>(cursor, bsum, N);
    k_scan_final<<<nb, SCB, 0, stream>>>(cursor, bsum, rowptr, N, nb);
    k_cursor<<<gN, b, 0, stream>>>(rowptr, cursor, N);
    k_scatter<<<gE, b, 0, stream>>>(ei, cursor, csr_src, csr_aid, E2, EU);

    dim3 gW((N + 3) / 4);   // 4 waves per block, 1 wave per node

    // ---- layer 1 (24 -> 24): ~27.0KB LDS -> 6 blocks/CU ----
    k_xform<24, 24><<<gN, b, 0, stream>>>(h, c1_wl, c1_bl, c1_wr, c1_br, xl, xr, N);
    k_gat<24, 6><<<gW, b, 0, stream>>>(rowptr, csr_src, csr_aid, eattr, xl, xr,
                                       c1_we, edge_w, edge_b, c1_att, c1_bias, h, N);

    // ---- layer 2 (24 -> 36): ~40.0KB LDS -> 4 blocks/CU ----
    k_xform<24, 36><<<gN, b, 0, stream>>>(h, c2_wl, c2_bl, c2_wr, c2_br, xl, xr, N);
    k_gat<36, 4><<<gW, b, 0, stream>>>(rowptr, csr_src, csr_aid, eattr, xl, xr,
                                       c2_we, edge_w, edge_b, c2_att, c2_bias, h, N);

    // ---- pool + head ----
    k_pool<<<G, b, 0, stream>>>(h, batch, pmean, N);
    k_final<<<(G * 64 + TPB - 1) / TPB, b, 0, stream>>>(pmean, fin_w, fin_b, out, G);
}